// Round 1
// baseline (517.802 us; speedup 1.0000x reference)
//
#include <hip/hip_runtime.h>
#include <hip/hip_bf16.h>
#include <hip/hip_cooperative_groups.h>

namespace cg = cooperative_groups;

// CapsuleLayerWithRouting: batch=128, in_caps=1152, in_hid=16, out_caps=32,
// out_hid=16, 3 routing iterations (fixed). fp32 in/out.
//
// Round-6: single cooperative kernel fusing all 8 previous launches.
//  - phases: conv(W->Wb bf16 frags) | pass1 | reduce0 | pass2 | reduce1 |
//    pass3 | reduce2(out), separated by cg grid syncs (6 total)
//  - X fragments staged into LDS ONCE, persist across all 3 passes
//  - blocks pinned to CUs for the whole run -> Wb slice (288 KB) and P slice
//    stay in the local per-XCD L2 across passes (8 iblk x 8 bg per XCD)
//  - LDS union: conv staging st[16][516] (33KB) overlaps xs[18][64][4]+part
//  - fallback to the verified round-5 8-kernel path if cooperative launch
//    is rejected (returns error without enqueuing -> no regression)
// Fragment layouts (HW-verified m89/m91):
//   A[m=lane&15][k=(lane>>4)*8+j]  B[k=(lane>>4)*8+j][n=lane&15]
//   D[row=(lane>>4)*4+reg][col=lane&15]

#define IN_CAPS 1152
#define OUT_CAPS 32
#define BATCH 128
#define IPC 18
#define NBLK_I (IN_CAPS / IPC)               // 64
#define SV_ELEMS (BATCH * OUT_CAPS * 16)     // 65536
#define GRID 512

typedef __attribute__((ext_vector_type(8))) short short8;
typedef __attribute__((ext_vector_type(4))) float f32x4;

__device__ inline unsigned f2bf(float x) {          // RNE fp32 -> bf16
  unsigned u = __builtin_bit_cast(unsigned, x);
  return (u + 0x7FFFu + ((u >> 16) & 1u)) >> 16;
}

// ---- build x B-fragment slice in LDS: xs[i][lane][4 uints] (16B/lane),
// zeros in lanes 32-63 (the k=16..31 zero pad) ----
__device__ __forceinline__ void build_xs(const float* __restrict__ X, int bg,
                                         int i0, int t, unsigned (*xs)[64][4]) {
#pragma unroll
  for (int rep = 0; rep < IPC * 256 / 512; ++rep) {
    const int base = rep * 512 + t;
    const int ii = base >> 8;
    const int e = base & 255;
    const int l2 = e >> 2, ju = e & 3;
    unsigned val = 0;
    if (l2 < 32) {
      const float2 f = *(const float2*)(X +
          ((size_t)(bg * 16 + (l2 & 15)) * IN_CAPS + (i0 + ii)) * 16 +
          (l2 >> 4) * 8 + 2 * ju);
      val = f2bf(f.x) | (f2bf(f.y) << 16);
    }
    xs[ii][l2][ju] = val;
  }
}

__device__ __forceinline__ short8 ld_x(const unsigned (*xs)[64][4], int ii, int l) {
  return __builtin_bit_cast(short8, *(const uint4*)(&xs[ii][l][0]));
}

// ---- convert one i of W [16][512] fp32 -> A-fragments, 512 threads ----
__device__ __forceinline__ void conv_i(const float* __restrict__ W,
                                       unsigned short* __restrict__ Wb,
                                       float* st, int i, int t) {
  const float4* src = (const float4*)(W + (size_t)i * 8192);
#pragma unroll
  for (int r = 0; r < 4; ++r) {
    const int f = r * 512 + t;                // 0..2047 float4s
    const int k = f >> 7, c4 = f & 127;
    *(float4*)&st[k * 516 + c4 * 4] = src[f];
  }
  __syncthreads();
  unsigned short* dst = Wb + (size_t)i * 8192;
#pragma unroll
  for (int r = 0; r < 2; ++r) {
    const int uu = r * 512 + t;               // 0..1023 = o*32 + l
    const int o = uu >> 5, ll = uu & 31;
    const int col = o * 16 + (ll & 15), k0 = (ll >> 4) * 8;
    unsigned b[8];
#pragma unroll
    for (int j = 0; j < 8; ++j) b[j] = f2bf(st[(k0 + j) * 516 + col]);
    uint4 outv;
    outv.x = b[0] | (b[1] << 16);
    outv.y = b[2] | (b[3] << 16);
    outv.z = b[4] | (b[5] << 16);
    outv.w = b[6] | (b[7] << 16);
    *(uint4*)(dst + (size_t)uu * 8) = outv;   // consecutive uu -> coalesced
  }
  __syncthreads();                            // st reused by next i
}

// ---- pass 1 body: C = 1/32 uniform -> S1 partials ----
__device__ __forceinline__ void pass1_phase(const short8* __restrict__ wpb,
                                            const unsigned (*xs)[64][4],
                                            float* __restrict__ pp, int l) {
  const short8* wp = wpb;
  f32x4 sacc[4];
#pragma unroll
  for (int m = 0; m < 4; ++m) sacc[m] = (f32x4){0.f, 0.f, 0.f, 0.f};
  for (int ii = 0; ii < IPC; ++ii) {
    short8 x = ld_x(xs, ii, l);
    short8 a0 = wp[0], a1 = wp[32], a2 = wp[64], a3 = wp[96];
    wp += 1024;
    sacc[0] = __builtin_amdgcn_mfma_f32_16x16x32_bf16(a0, x, sacc[0], 0, 0, 0);
    sacc[1] = __builtin_amdgcn_mfma_f32_16x16x32_bf16(a1, x, sacc[1], 0, 0, 0);
    sacc[2] = __builtin_amdgcn_mfma_f32_16x16x32_bf16(a2, x, sacc[2], 0, 0, 0);
    sacc[3] = __builtin_amdgcn_mfma_f32_16x16x32_bf16(a3, x, sacc[3], 0, 0, 0);
  }
#pragma unroll
  for (int m = 0; m < 4; ++m) *(f32x4*)(pp + m * 16) = sacc[m] * (1.f / 32.f);
}

// ---- passes 2/3 body: dot = u.V; C = softmax(dot); S += C*u ----
__device__ __forceinline__ void pass23_phase(const short8* __restrict__ wpb,
                                             const unsigned (*xs)[64][4],
                                             float (*part)[8][16],
                                             const float* __restrict__ Vt,
                                             float* __restrict__ pp,
                                             int bg, int w, int l, int q, int bl) {
  f32x4 v[4], sacc[4];
#pragma unroll
  for (int m = 0; m < 4; ++m) {
    v[m] = ((const f32x4*)Vt)[((size_t)(bg * 8 + w) * 64 + l) * 4 + m];
    sacc[m] = (f32x4){0.f, 0.f, 0.f, 0.f};
  }

  const short8* wp = wpb;
  short8 an[4];
  short8 xn = ld_x(xs, 0, l);
#pragma unroll
  for (int m = 0; m < 4; ++m) an[m] = wp[m * 32];
  wp += 1024;

  for (int ii = 0; ii < IPC; ++ii) {
    short8 ac[4];
#pragma unroll
    for (int m = 0; m < 4; ++m) ac[m] = an[m];
    short8 xc = xn;
    if (ii + 1 < IPC) {                      // prefetch rides across barrier
      xn = ld_x(xs, ii + 1, l);
#pragma unroll
      for (int m = 0; m < 4; ++m) an[m] = wp[m * 32];
      wp += 1024;
    }

    const f32x4 z = {0.f, 0.f, 0.f, 0.f};
    f32x4 d[4];
#pragma unroll
    for (int m = 0; m < 4; ++m)
      d[m] = __builtin_amdgcn_mfma_f32_16x16x32_bf16(ac[m], xc, z, 0, 0, 0);
    // d[m][r] = U[o=w*4+m][h=q*4+r][b=bl]

    float e[4];
#pragma unroll
    for (int m = 0; m < 4; ++m) {
      f32x4 pr = d[m] * v[m];
      float p = (pr[0] + pr[1]) + (pr[2] + pr[3]);
      p += __shfl_xor(p, 16);
      p += __shfl_xor(p, 32);
      e[m] = __expf(p);
    }
    const float esum = (e[0] + e[1]) + (e[2] + e[3]);
    if (q == 0) part[ii & 1][w][bl] = esum;
    __syncthreads();
    float den = 0.f;
#pragma unroll
    for (int ww = 0; ww < 8; ++ww) den += part[ii & 1][ww][bl];
    const float rden = __builtin_amdgcn_rcpf(den);
#pragma unroll
    for (int m = 0; m < 4; ++m) sacc[m] += d[m] * (e[m] * rden);
    // part[parity] reuse two iters later is fenced by the barrier in between
  }

#pragma unroll
  for (int m = 0; m < 4; ++m) *(f32x4*)(pp + m * 16) = sacc[m];
}

// ---- reduce over iblk + squash. MODE 0: V1p + Vt. 1: Vt = V1p+sq. 2: Out. --
template <int MODE>
__device__ __forceinline__ void reduce_phase(const float* __restrict__ P,
                                             float* __restrict__ Vt,
                                             float* __restrict__ V1p,
                                             float* __restrict__ Out, int j) {
  if (j < SV_ELEMS) {
    float s = 0.f;
    const float* p = P + j;
#pragma unroll 8
    for (int k = 0; k < NBLK_I; ++k) s += p[(size_t)k * SV_ELEMS];
    float ns = s * s;
    ns += __shfl_xor(ns, 1);
    ns += __shfl_xor(ns, 2);
    ns += __shfl_xor(ns, 4);
    ns += __shfl_xor(ns, 8);
    const float sc = ns / ((1.f + ns) * sqrtf(ns));
    float vv = s * sc;
    if constexpr (MODE == 2) {
      Out[j] = vv;
    } else {
      if constexpr (MODE == 0) V1p[j] = vv;
      if constexpr (MODE == 1) vv += V1p[j];
      const int b = j >> 9, oh = j & 511, o = oh >> 4, h = oh & 15;
      const int bg = b >> 4, bl = b & 15, w = o >> 2, m = o & 3, qq = h >> 2;
      Vt[(((size_t)(bg * 8 + w) * 64 + qq * 16 + bl) * 16) + m * 4 + (h & 3)] = vv;
    }
  }
}

// =================== fused cooperative kernel ===================
__global__ __launch_bounds__(512, 4)
void caps_fused(const float* __restrict__ W, const float* __restrict__ X,
                unsigned short* __restrict__ Wb, float* __restrict__ P,
                float* __restrict__ Vt, float* __restrict__ V1p,
                float* __restrict__ Out) {
  // LDS union: conv st[16*516] (33024B) overlaps xs (18432B) + part (1024B)
  __shared__ __align__(16) char smem[16 * 516 * 4];
  float* st = (float*)smem;
  unsigned (*xs)[64][4] = (unsigned (*)[64][4])smem;
  float (*part)[8][16] = (float (*)[8][16])(smem + IPC * 64 * 16);

  const int t = threadIdx.x, w = t >> 6, l = t & 63;
  const int q = l >> 4, bl = l & 15;
  const int bid = blockIdx.x, iblk = bid & 63, bg = bid >> 6;
  const int i0 = iblk * IPC;
  const int gt = bid * 512 + t;
  cg::grid_group grid = cg::this_grid();

  // phase 0: W -> Wb (blocks stride over i; 2-3 each)
  for (int i = bid; i < IN_CAPS; i += GRID) conv_i(W, Wb, st, i, t);

  // stage X fragments ONCE; conv's trailing __syncthreads fences st aliasing
  build_xs(X, bg, i0, t, xs);
  __syncthreads();
  grid.sync();                                        // Wb complete everywhere

  const short8* wpb = (const short8*)Wb + ((size_t)i0 * 32 + w * 4) * 32 + (l & 31);
  float* pp = P + ((size_t)iblk * 128 + bg * 16 + bl) * 512 + w * 64 + q * 4;

  pass1_phase(wpb, xs, pp, l);                        // routing iter 1
  grid.sync();
  reduce_phase<0>(P, Vt, V1p, nullptr, gt);
  grid.sync();
  pass23_phase(wpb, xs, part, Vt, pp, bg, w, l, q, bl); // routing iter 2
  grid.sync();
  reduce_phase<1>(P, Vt, V1p, nullptr, gt);
  grid.sync();
  pass23_phase(wpb, xs, part, Vt, pp, bg, w, l, q, bl); // routing iter 3
  grid.sync();
  reduce_phase<2>(P, nullptr, nullptr, Out, gt);
}

// =================== fallback: round-5 kernels ===================
__global__ __launch_bounds__(256) void conv_w(const float* __restrict__ W,
                                              unsigned short* __restrict__ Wb) {
  __shared__ float st[16 * 516];
  const int t = threadIdx.x;
  const size_t ibase = (size_t)blockIdx.x * 8192;
  const float4* src = (const float4*)(W + ibase);
#pragma unroll
  for (int r = 0; r < 8; ++r) {
    const int f = r * 256 + t;
    const int k = f >> 7, c4 = f & 127;
    *(float4*)&st[k * 516 + c4 * 4] = src[f];
  }
  __syncthreads();
  unsigned short* dst = Wb + ibase;
#pragma unroll
  for (int r = 0; r < 4; ++r) {
    const int u = r * 256 + t;
    const int o = u >> 5, l = u & 31;
    const int col = o * 16 + (l & 15), k0 = (l >> 4) * 8;
    unsigned b[8];
#pragma unroll
    for (int j = 0; j < 8; ++j) b[j] = f2bf(st[(k0 + j) * 516 + col]);
    uint4 outv;
    outv.x = b[0] | (b[1] << 16);
    outv.y = b[2] | (b[3] << 16);
    outv.z = b[4] | (b[5] << 16);
    outv.w = b[6] | (b[7] << 16);
    *(uint4*)(dst + (size_t)u * 8) = outv;
  }
}

__global__ __launch_bounds__(512, 4)
void caps_pass1(const unsigned short* __restrict__ Wb,
                const float* __restrict__ X, float* __restrict__ P) {
  __shared__ __align__(16) unsigned xs[IPC][64][4];
  const int t = threadIdx.x, w = t >> 6, l = t & 63;
  const int q = l >> 4, bl = l & 15;
  const int gx = blockIdx.x, iblk = gx & 63, bg = gx >> 6;
  const int i0 = iblk * IPC;
  build_xs(X, bg, i0, t, xs);
  __syncthreads();
  const short8* wpb = (const short8*)Wb + ((size_t)i0 * 32 + w * 4) * 32 + (l & 31);
  float* pp = P + ((size_t)iblk * 128 + bg * 16 + bl) * 512 + w * 64 + q * 4;
  pass1_phase(wpb, xs, pp, l);
}

__global__ __launch_bounds__(512, 4)
void caps_pass23(const unsigned short* __restrict__ Wb,
                 const float* __restrict__ X,
                 const float* __restrict__ Vt, float* __restrict__ P) {
  __shared__ __align__(16) unsigned xs[IPC][64][4];
  __shared__ float part[2][8][16];
  const int t = threadIdx.x, w = t >> 6, l = t & 63;
  const int q = l >> 4, bl = l & 15;
  const int gx = blockIdx.x, iblk = gx & 63, bg = gx >> 6;
  const int i0 = iblk * IPC;
  build_xs(X, bg, i0, t, xs);
  __syncthreads();
  const short8* wpb = (const short8*)Wb + ((size_t)i0 * 32 + w * 4) * 32 + (l & 31);
  float* pp = P + ((size_t)iblk * 128 + bg * 16 + bl) * 512 + w * 64 + q * 4;
  pass23_phase(wpb, xs, part, Vt, pp, bg, w, l, q, bl);
}

template <int MODE>
__global__ __launch_bounds__(256)
void reduce_squash(const float* __restrict__ P, float* __restrict__ Vt,
                   float* __restrict__ V1p, float* __restrict__ Out) {
  const int j = blockIdx.x * 256 + threadIdx.x;
  reduce_phase<MODE>(P, Vt, V1p, Out, j);
}

extern "C" void kernel_launch(void* const* d_in, const int* in_sizes, int n_in,
                              void* d_out, int out_size, void* d_ws, size_t ws_size,
                              hipStream_t stream) {
  const float* X  = (const float*)d_in[0];
  const float* Wg = (const float*)d_in[1];
  // d_in[2] = routing_iterations (3, hard-coded)

  float* P   = (float*)d_ws;                         // 64*65536 f = 16.8 MB
  float* Vt  = P + (size_t)NBLK_I * SV_ELEMS;        // 65536 f (frag order)
  float* V1p = Vt + SV_ELEMS;                        // 65536 f (plain)
  unsigned short* Wb = (unsigned short*)(V1p + SV_ELEMS);   // 18.9 MB
  float* out = (float*)d_out;                        // total ws ~36.3 MB

  void* args[] = {(void*)&Wg, (void*)&X, (void*)&Wb, (void*)&P,
                  (void*)&Vt, (void*)&V1p, (void*)&out};
  hipError_t err = hipLaunchCooperativeKernel((void*)caps_fused, dim3(GRID),
                                              dim3(512), args, 0, stream);
  if (err != hipSuccess) {
    (void)hipGetLastError();                         // clear, take 8-kernel path
    conv_w<<<IN_CAPS, 256, 0, stream>>>(Wg, Wb);
    caps_pass1<<<512, 512, 0, stream>>>(Wb, X, P);
    reduce_squash<0><<<256, 256, 0, stream>>>(P, Vt, V1p, nullptr);
    caps_pass23<<<512, 512, 0, stream>>>(Wb, X, Vt, P);
    reduce_squash<1><<<256, 256, 0, stream>>>(P, Vt, V1p, nullptr);
    caps_pass23<<<512, 512, 0, stream>>>(Wb, X, Vt, P);
    reduce_squash<2><<<256, 256, 0, stream>>>(P, nullptr, nullptr, out);
  }
}

// Round 2
// 161.435 us; speedup vs baseline: 3.2075x; 3.2075x over previous
//
#include <hip/hip_runtime.h>
#include <hip/hip_bf16.h>

// CapsuleLayerWithRouting: batch=128, in_caps=1152, in_hid=16, out_caps=32,
// out_hid=16, 3 routing iterations (fixed). fp32 in/out.
//
// Round-7: revert to the verified 7-kernel structure (round-5, 165 us).
// Round-6 post-mortem: cg grid.sync() ~50 us/sync on gfx950 -> fusion dead;
// dur_us includes ~86 us of harness workspace-poison fills, so the
// controllable budget is ~79 us of kernels+gaps. This round attacks the two
// modeled hot spots inside that budget:
//  - pass23: 2 routing-i per __syncthreads (9 barriers instead of 18) via a
//    4-slot part[] ring (same 2-deep WAR fencing as the old parity trick);
//    d is pre-scaled by e before the barrier so i+1's MFMAs issue BEFORE the
//    barrier (pipeline fill), and only d*e (32 VGPR) is live across it.
//  - reduce_squash: float4 loads (16B/lane), k-loop split 8-way across the
//    block with an LDS combine, grid spread 256->512 blocks.
// Fragment layouts (HW-verified m89/m91):
//   A[m=lane&15][k=(lane>>4)*8+j]  B[k=(lane>>4)*8+j][n=lane&15]
//   D[row=(lane>>4)*4+reg][col=lane&15]

#define IN_CAPS 1152
#define OUT_CAPS 32
#define BATCH 128
#define IPC 18
#define NBLK_I (IN_CAPS / IPC)               // 64
#define SV_ELEMS (BATCH * OUT_CAPS * 16)     // 65536

typedef __attribute__((ext_vector_type(8))) short short8;
typedef __attribute__((ext_vector_type(4))) float f32x4;

__device__ inline unsigned f2bf(float x) {          // RNE fp32 -> bf16
  unsigned u = __builtin_bit_cast(unsigned, x);
  return (u + 0x7FFFu + ((u >> 16) & 1u)) >> 16;
}

// ---- W [1152][16][512] fp32 -> Wb [i][o][lane(32)][8] bf16 (A-frag). ----
// One i per block; LDS-staged so global reads and writes are both coalesced.
__global__ __launch_bounds__(256) void conv_w(const float* __restrict__ W,
                                              unsigned short* __restrict__ Wb) {
  __shared__ float st[16 * 516];              // stride 516: 2-way banks only
  const int t = threadIdx.x;
  const size_t ibase = (size_t)blockIdx.x * 8192;
  const float4* src = (const float4*)(W + ibase);
#pragma unroll
  for (int r = 0; r < 8; ++r) {
    const int f = r * 256 + t;                // 0..2047 float4s
    const int k = f >> 7, c4 = f & 127;
    *(float4*)&st[k * 516 + c4 * 4] = src[f];
  }
  __syncthreads();
  unsigned short* dst = Wb + ibase;
#pragma unroll
  for (int r = 0; r < 4; ++r) {
    const int u = r * 256 + t;                // 0..1023 = o*32 + l
    const int o = u >> 5, l = u & 31;
    const int col = o * 16 + (l & 15), k0 = (l >> 4) * 8;
    unsigned b[8];
#pragma unroll
    for (int j = 0; j < 8; ++j) b[j] = f2bf(st[(k0 + j) * 516 + col]);
    uint4 outv;
    outv.x = b[0] | (b[1] << 16);
    outv.y = b[2] | (b[3] << 16);
    outv.z = b[4] | (b[5] << 16);
    outv.w = b[6] | (b[7] << 16);
    *(uint4*)(dst + (size_t)u * 8) = outv;    // consecutive u -> coalesced
  }
}

// ---- build x B-fragment slice in LDS: xs[i][lane][4 uints] (16B/lane),
// zeros in lanes 32-63 (the k=16..31 zero pad) ----
__device__ __forceinline__ void build_xs(const float* __restrict__ X, int bg,
                                         int i0, int t, unsigned (*xs)[64][4]) {
#pragma unroll
  for (int rep = 0; rep < IPC * 256 / 512; ++rep) {
    const int base = rep * 512 + t;
    const int ii = base >> 8;
    const int e = base & 255;
    const int l2 = e >> 2, ju = e & 3;
    unsigned val = 0;
    if (l2 < 32) {
      const float2 f = *(const float2*)(X +
          ((size_t)(bg * 16 + (l2 & 15)) * IN_CAPS + (i0 + ii)) * 16 +
          (l2 >> 4) * 8 + 2 * ju);
      val = f2bf(f.x) | (f2bf(f.y) << 16);
    }
    xs[ii][l2][ju] = val;
  }
}

__device__ __forceinline__ short8 ld_x(const unsigned (*xs)[64][4], int ii, int l) {
  return __builtin_bit_cast(short8, *(const uint4*)(&xs[ii][l][0]));
}

// ---- pass 1: C = 1/32 uniform -> S1 partials ----
__global__ __launch_bounds__(512, 4)
void caps_pass1(const unsigned short* __restrict__ Wb,
                const float* __restrict__ X, float* __restrict__ P) {
  __shared__ __align__(16) unsigned xs[IPC][64][4];
  const int t = threadIdx.x, w = t >> 6, l = t & 63;
  const int q = l >> 4, bl = l & 15;
  const int gx = blockIdx.x, iblk = gx & 63, bg = gx >> 6;
  const int i0 = iblk * IPC;

  build_xs(X, bg, i0, t, xs);
  __syncthreads();

  const short8* wp = (const short8*)Wb + ((size_t)i0 * 32 + w * 4) * 32 + (l & 31);
  f32x4 sacc[4];
#pragma unroll
  for (int m = 0; m < 4; ++m) sacc[m] = (f32x4){0.f, 0.f, 0.f, 0.f};

  for (int ii = 0; ii < IPC; ++ii) {
    short8 x = ld_x(xs, ii, l);
    short8 a0 = wp[0], a1 = wp[32], a2 = wp[64], a3 = wp[96];
    wp += 1024;
    sacc[0] = __builtin_amdgcn_mfma_f32_16x16x32_bf16(a0, x, sacc[0], 0, 0, 0);
    sacc[1] = __builtin_amdgcn_mfma_f32_16x16x32_bf16(a1, x, sacc[1], 0, 0, 0);
    sacc[2] = __builtin_amdgcn_mfma_f32_16x16x32_bf16(a2, x, sacc[2], 0, 0, 0);
    sacc[3] = __builtin_amdgcn_mfma_f32_16x16x32_bf16(a3, x, sacc[3], 0, 0, 0);
  }
  float* pp = P + ((size_t)iblk * 128 + bg * 16 + bl) * 512 + w * 64 + q * 4;
#pragma unroll
  for (int m = 0; m < 4; ++m) *(f32x4*)(pp + m * 16) = sacc[m] * (1.f / 32.f);
}

// ---- passes 2/3: dot = u.V; C = softmax(dot); S += C*u.
// Two routing-i per barrier; part[] is a 4-slot ring so a slot is rewritten
// two pairs later, always with an intervening barrier (WAR-safe). ----
__global__ __launch_bounds__(512, 4)
void caps_pass23(const unsigned short* __restrict__ Wb,
                 const float* __restrict__ X,
                 const float* __restrict__ Vt,   // fragment order
                 float* __restrict__ P) {
  __shared__ __align__(16) unsigned xs[IPC][64][4];
  __shared__ float part[4][8][16];
  const int t = threadIdx.x, w = t >> 6, l = t & 63;
  const int q = l >> 4, bl = l & 15;
  const int gx = blockIdx.x, iblk = gx & 63, bg = gx >> 6;
  const int i0 = iblk * IPC;

  f32x4 v[4], sacc[4];
#pragma unroll
  for (int m = 0; m < 4; ++m) {
    v[m] = ((const f32x4*)Vt)[((size_t)(bg * 8 + w) * 64 + l) * 4 + m];
    sacc[m] = (f32x4){0.f, 0.f, 0.f, 0.f};
  }

  build_xs(X, bg, i0, t, xs);
  __syncthreads();

  const short8* wp = (const short8*)Wb + ((size_t)i0 * 32 + w * 4) * 32 + (l & 31);
  short8 an[4];
  short8 xn = ld_x(xs, 0, l);
#pragma unroll
  for (int m = 0; m < 4; ++m) an[m] = wp[m * 32];
  wp += 1024;

  for (int pr2 = 0; pr2 < IPC / 2; ++pr2) {
    f32x4 dk0[4], dk1[4];
    const int s0 = (pr2 & 1) * 2;            // part slot pair for this pr2
    // ---- half 0 (ii = 2*pr2) ----
    {
      short8 ac[4];
      short8 xc = xn;
#pragma unroll
      for (int m = 0; m < 4; ++m) ac[m] = an[m];
      xn = ld_x(xs, 2 * pr2 + 1, l);         // always valid (<= 17)
#pragma unroll
      for (int m = 0; m < 4; ++m) an[m] = wp[m * 32];
      wp += 1024;
      const f32x4 z = {0.f, 0.f, 0.f, 0.f};
      f32x4 d[4];
      float e[4];
#pragma unroll
      for (int m = 0; m < 4; ++m)
        d[m] = __builtin_amdgcn_mfma_f32_16x16x32_bf16(ac[m], xc, z, 0, 0, 0);
#pragma unroll
      for (int m = 0; m < 4; ++m) {
        f32x4 pm = d[m] * v[m];
        float p = (pm[0] + pm[1]) + (pm[2] + pm[3]);
        p += __shfl_xor(p, 16);
        p += __shfl_xor(p, 32);
        e[m] = __expf(p);
      }
      if (q == 0) part[s0][w][bl] = (e[0] + e[1]) + (e[2] + e[3]);
#pragma unroll
      for (int m = 0; m < 4; ++m) dk0[m] = d[m] * e[m];   // pre-scale by e
    }
    // ---- half 1 (ii = 2*pr2+1); its MFMAs issue BEFORE the barrier ----
    {
      const int ii = 2 * pr2 + 1;
      short8 ac[4];
      short8 xc = xn;
#pragma unroll
      for (int m = 0; m < 4; ++m) ac[m] = an[m];
      if (ii + 1 < IPC) {                    // prefetch rides across barrier
        xn = ld_x(xs, ii + 1, l);
#pragma unroll
        for (int m = 0; m < 4; ++m) an[m] = wp[m * 32];
        wp += 1024;
      }
      const f32x4 z = {0.f, 0.f, 0.f, 0.f};
      f32x4 d[4];
      float e[4];
#pragma unroll
      for (int m = 0; m < 4; ++m)
        d[m] = __builtin_amdgcn_mfma_f32_16x16x32_bf16(ac[m], xc, z, 0, 0, 0);
#pragma unroll
      for (int m = 0; m < 4; ++m) {
        f32x4 pm = d[m] * v[m];
        float p = (pm[0] + pm[1]) + (pm[2] + pm[3]);
        p += __shfl_xor(p, 16);
        p += __shfl_xor(p, 32);
        e[m] = __expf(p);
      }
      if (q == 0) part[s0 + 1][w][bl] = (e[0] + e[1]) + (e[2] + e[3]);
#pragma unroll
      for (int m = 0; m < 4; ++m) dk1[m] = d[m] * e[m];
    }
    __syncthreads();                         // one barrier per TWO routing-i
    float den0 = 0.f, den1 = 0.f;
#pragma unroll
    for (int ww = 0; ww < 8; ++ww) {
      den0 += part[s0][ww][bl];
      den1 += part[s0 + 1][ww][bl];
    }
    const float r0 = __builtin_amdgcn_rcpf(den0);
    const float r1 = __builtin_amdgcn_rcpf(den1);
#pragma unroll
    for (int m = 0; m < 4; ++m) sacc[m] += dk0[m] * r0 + dk1[m] * r1;
    // slot pair s0 is rewritten two pairs later; the next pair's barrier
    // sits between this read and that write (same fencing as old parity).
  }

  float* pp = P + ((size_t)iblk * 128 + bg * 16 + bl) * 512 + w * 64 + q * 4;
#pragma unroll
  for (int m = 0; m < 4; ++m) *(f32x4*)(pp + m * 16) = sacc[m];
}

// ---- reduce over iblk + squash. MODE 0: V1p + Vt. 1: Vt = V1p+sq. 2: Out.
// float4 loads, k-loop split 8-way across the block, 512-block spread. ----
template <int MODE>
__global__ __launch_bounds__(256)
void reduce_squash(const float* __restrict__ P, float* __restrict__ Vt,
                   float* __restrict__ V1p, float* __restrict__ Out) {
  __shared__ f32x4 red[8][32];
  const int t = threadIdx.x, qd = t & 31, kq = t >> 5;
  const int j4 = blockIdx.x * 32 + qd;             // quad index, 0..16383
  const f32x4* p = (const f32x4*)P + j4 + (size_t)kq * 8 * (SV_ELEMS / 4);
  f32x4 s = {0.f, 0.f, 0.f, 0.f};
#pragma unroll
  for (int k = 0; k < 8; ++k) s += p[(size_t)k * (SV_ELEMS / 4)];
  red[kq][qd] = s;
  __syncthreads();
  if (t < 32) {
    f32x4 a = red[0][t];
#pragma unroll
    for (int k2 = 1; k2 < 8; ++k2) a += red[k2][t];
    // norm over 16 h: 4 in-thread + quads j4^1, j4^2 (h-quarters)
    float ns = a[0] * a[0] + a[1] * a[1] + a[2] * a[2] + a[3] * a[3];
    ns += __shfl_xor(ns, 1);
    ns += __shfl_xor(ns, 2);
    const float sc = ns / ((1.f + ns) * sqrtf(ns));
    f32x4 vv = a * sc;
    if constexpr (MODE == 2) {
      ((f32x4*)Out)[j4] = vv;
    } else {
      if constexpr (MODE == 0) ((f32x4*)V1p)[j4] = vv;
      if constexpr (MODE == 1) vv += ((const f32x4*)V1p)[j4];
#pragma unroll
      for (int c = 0; c < 4; ++c) {
        const int j = j4 * 4 + c;
        const int b = j >> 9, oh = j & 511, o = oh >> 4, h = oh & 15;
        const int bg = b >> 4, bl = b & 15, w = o >> 2, m = o & 3, qq = h >> 2;
        Vt[(((size_t)(bg * 8 + w) * 64 + qq * 16 + bl) * 16) + m * 4 + (h & 3)] =
            vv[c];
      }
    }
  }
}

extern "C" void kernel_launch(void* const* d_in, const int* in_sizes, int n_in,
                              void* d_out, int out_size, void* d_ws, size_t ws_size,
                              hipStream_t stream) {
  const float* X  = (const float*)d_in[0];
  const float* Wg = (const float*)d_in[1];
  // d_in[2] = routing_iterations (3, hard-coded)

  float* P   = (float*)d_ws;                         // 64*65536 f = 16.8 MB
  float* Vt  = P + (size_t)NBLK_I * SV_ELEMS;        // 65536 f (frag order)
  float* V1p = Vt + SV_ELEMS;                        // 65536 f (plain)
  unsigned short* Wb = (unsigned short*)(V1p + SV_ELEMS);   // 18.9 MB
  float* out = (float*)d_out;                        // total ws ~36.3 MB

  conv_w<<<IN_CAPS, 256, 0, stream>>>(Wg, Wb);

  caps_pass1<<<512, 512, 0, stream>>>(Wb, X, P);
  reduce_squash<0><<<512, 256, 0, stream>>>(P, Vt, V1p, nullptr);

  caps_pass23<<<512, 512, 0, stream>>>(Wb, X, Vt, P);
  reduce_squash<1><<<512, 256, 0, stream>>>(P, Vt, V1p, nullptr);

  caps_pass23<<<512, 512, 0, stream>>>(Wb, X, Vt, P);
  reduce_squash<2><<<512, 256, 0, stream>>>(P, nullptr, nullptr, out);
}